// Round 16
// baseline (244.428 us; speedup 1.0000x reference)
//
#include <hip/hip_runtime.h>
#include <hip/hip_cooperative_groups.h>

namespace cg = cooperative_groups;

#define N_NODES 50000
#define N_EDGES 800000
#define DIN 256
#define DOUT 64
#define LN_EPS 1e-5f
#define NB 782        // buckets of 64 dsts (= 2 * GRID exactly)
#define BCAP 2048     // bucket capacity (mean 1024, sd ~32)
#define GRID 391      // blocks; gemm 128 rows/block * 391 = 50048 >= 50000
#define EPB 2048      // partition edges/block: 391 * 2048 = 800768 >= 800000

typedef __attribute__((ext_vector_type(8))) short bfrag8;
typedef __attribute__((ext_vector_type(4))) float f32x4;

__device__ inline unsigned short f2bf(float f) {
    unsigned u = __builtin_bit_cast(unsigned, f);
    u += 0x7fffu + ((u >> 16) & 1u);          // round-to-nearest-even
    return (unsigned short)(u >> 16);
}
__device__ inline float bf2f(unsigned short b) {
    unsigned u = ((unsigned)b) << 16;
    return __builtin_bit_cast(float, u);
}

// One cooperative kernel: zero -> partition -> sort/dinv -> gemm -> agg+LN,
// grid.sync() replacing 4 kernel boundaries (tests the ~20us gap theory).
// LDS: 32KB raw arena re-cast per phase (max user = gemm W tile).
// __launch_bounds__(512,4): VGPR<=128 -> >=2 blocks/CU -> 391 blocks co-resident.
__global__ __launch_bounds__(512, 4) void fused_kernel(
    const float* __restrict__ xs, const int* __restrict__ ei,
    const float* __restrict__ W, const float* __restrict__ bias,
    const float* __restrict__ gamma, const float* __restrict__ beta,
    int* __restrict__ gcur, float* __restrict__ dinv,
    unsigned* __restrict__ bdata, unsigned short* __restrict__ hs,
    int* __restrict__ nstart, int* __restrict__ nend, float* __restrict__ out) {
    cg::grid_group grid = cg::this_grid();
    __shared__ __align__(16) char smraw[32768];
    const int tid = threadIdx.x;

    // ---------- phase 0: zero gcur ----------
    {
        int i = blockIdx.x * 512 + tid;
        if (i < NB) gcur[i] = 0;
    }
    grid.sync();

    // ---------- phase 1: partition (bucket edges by dst/64, rank trick) ------
    {
        int* hist  = (int*)smraw;
        int* hbase = hist + NB;
        for (int c = tid; c < NB; c += 512) hist[c] = 0;
        __syncthreads();
        const int chunk = blockIdx.x * EPB;
        unsigned u[4]; int bk[4]; int rk[4];
        #pragma unroll
        for (int i = 0; i < 4; ++i) {
            int e = chunk + i * 512 + tid;
            if (e < N_EDGES) {
                int s = ei[e];
                int d = ei[N_EDGES + e];
                u[i] = (unsigned)s | ((unsigned)(d & 63) << 17);
                bk[i] = d >> 6;
                rk[i] = atomicAdd(&hist[bk[i]], 1);
            } else { bk[i] = -1; u[i] = 0; rk[i] = 0; }
        }
        __syncthreads();
        for (int c = tid; c < NB; c += 512) {
            int n = hist[c];
            hbase[c] = n ? atomicAdd(&gcur[c], n) : 0;
        }
        __syncthreads();
        #pragma unroll
        for (int i = 0; i < 4; ++i) {
            if (bk[i] >= 0) {
                int off = hbase[bk[i]] + rk[i];
                if (off < BCAP) bdata[(size_t)bk[i] * BCAP + off] = u[i];
            }
        }
    }
    grid.sync();

    // ---------- phase 2: counting sort (2 buckets/block) + dinv + bounds -----
    {
        unsigned* buf = (unsigned*)smraw;            // 8KB
        int* hist = (int*)(smraw + BCAP * 4);
        int* pre  = hist + 64;
        #pragma unroll
        for (int t2 = 0; t2 < 2; ++t2) {
            int b = blockIdx.x * 2 + t2;             // 0..781, always valid
            if (tid < 64) hist[tid] = 0;
            __syncthreads();
            int cntb = gcur[b];
            if (cntb > BCAP) cntb = BCAP;
            unsigned* bd = bdata + (size_t)b * BCAP;
            unsigned v[4]; int rk[4];
            #pragma unroll
            for (int j = 0; j < 4; ++j) {
                int i = tid + j * 512;
                if (i < cntb) {
                    v[j] = bd[i];
                    rk[j] = atomicAdd(&hist[v[j] >> 17], 1);
                } else { v[j] = 0; rk[j] = -1; }
            }
            __syncthreads();
            if (tid < 64) {                          // wave 0: exclusive scan
                int n = hist[tid], s = n;
                #pragma unroll
                for (int d = 1; d < 64; d <<= 1) {
                    int t = __shfl_up(s, d, 64);
                    if (tid >= d) s += t;
                }
                pre[tid] = s - n;
                int node = b * 64 + tid;
                if (node < N_NODES) {
                    dinv[node] = rsqrtf((float)(n + 1));   // +1 self loop
                    nstart[node] = b * BCAP + (s - n);
                    nend[node]   = b * BCAP + s;
                }
            }
            __syncthreads();
            #pragma unroll
            for (int j = 0; j < 4; ++j) {
                if (rk[j] >= 0)
                    buf[pre[v[j] >> 17] + rk[j]] = v[j] & 0x1FFFF;   // src only
            }
            __syncthreads();
            #pragma unroll
            for (int j = 0; j < 4; ++j) {
                int i = tid + j * 512;
                if (i < cntb) bd[i] = buf[i];        // coalesced writeback
            }
            __syncthreads();
        }
    }
    grid.sync();

    // ---------- phase 3: MFMA GEMM, hs = (xs @ W^T) * dinv, bf16 -------------
    {
        bfrag8* wg = (bfrag8*)smraw;                 // 32KB bf16 W
        #pragma unroll
        for (int i = 0; i < 4; ++i) {
            int gi = tid + i * 512;                  // 0..2047
            int d = gi >> 5, g = gi & 31;
            const float* src = W + d * 256 + g * 8;
            f32x4 f0 = *(const f32x4*)src;
            f32x4 f1 = *(const f32x4*)(src + 4);
            union { unsigned short us[8]; bfrag8 v; } p;
            p.us[0] = f2bf(f0.x); p.us[1] = f2bf(f0.y);
            p.us[2] = f2bf(f0.z); p.us[3] = f2bf(f0.w);
            p.us[4] = f2bf(f1.x); p.us[5] = f2bf(f1.y);
            p.us[6] = f2bf(f1.z); p.us[7] = f2bf(f1.w);
            wg[d * 32 + (g ^ (d & 7))] = p.v;
        }
        __syncthreads();
        const int lane = tid & 63, wv = tid >> 6;
        const int n0 = (blockIdx.x * 8 + wv) * 16;
        int arow = n0 + (lane & 15);
        if (arow >= N_NODES) arow = N_NODES - 1;     // clamp (loads only)
        const float* xrow = xs + (size_t)arow * DIN + (lane >> 4) * 8;
        f32x4 acc[4] = {{0.f, 0.f, 0.f, 0.f}, {0.f, 0.f, 0.f, 0.f},
                        {0.f, 0.f, 0.f, 0.f}, {0.f, 0.f, 0.f, 0.f}};
        const int swz = lane & 7;
        #pragma unroll
        for (int s = 0; s < 8; ++s) {
            f32x4 xa = *(const f32x4*)(xrow + s * 32);
            f32x4 xb = *(const f32x4*)(xrow + s * 32 + 4);
            union { unsigned short us[8]; bfrag8 v; } a;
            a.us[0] = f2bf(xa.x); a.us[1] = f2bf(xa.y);
            a.us[2] = f2bf(xa.z); a.us[3] = f2bf(xa.w);
            a.us[4] = f2bf(xb.x); a.us[5] = f2bf(xb.y);
            a.us[6] = f2bf(xb.z); a.us[7] = f2bf(xb.w);
            int g = s * 4 + (lane >> 4);
            #pragma unroll
            for (int t = 0; t < 4; ++t) {
                bfrag8 b = wg[(t * 16 + (lane & 15)) * 32 + (g ^ swz)];
                acc[t] = __builtin_amdgcn_mfma_f32_16x16x32_bf16(a.v, b, acc[t], 0, 0, 0);
            }
        }
        // C/D: col = lane&15, row = (lane>>4)*4 + r ; scale by dinv on store
        #pragma unroll
        for (int t = 0; t < 4; ++t) {
            #pragma unroll
            for (int r = 0; r < 4; ++r) {
                int row = n0 + (lane >> 4) * 4 + r;
                if (row < N_NODES) {
                    float dr = dinv[row];
                    hs[(size_t)row * DOUT + t * 16 + (lane & 15)] = f2bf(acc[t][r] * dr);
                }
            }
        }
    }
    grid.sync();

    // ---------- phase 4: CSR aggregate + self loop + bias + LayerNorm --------
    // 4 nodes/wave, 16 lanes/node, uint2/lane (R12 best shape), grid-stride
    // over 12500 wave-tasks (3128 waves x 4 iterations, 12500*4 = 50000 exact).
    {
        const int lane = tid & 63, wv = tid >> 6;
        const int q = lane >> 4;
        const int fl = lane & 15;
        const int gw = blockIdx.x * 8 + wv;          // 0..3127
        for (int t = gw; t < 12500; t += GRID * 8) {
            const int node = t * 4 + q;              // < 50000 always
            const int c0 = nstart[node];
            const int deg = nend[node] - c0;
            const int cmax = deg > 0 ? deg - 1 : 0;
            uint2 sv = *(const uint2*)(hs + (size_t)node * DOUT + fl * 4);
            float a0 = bf2f((unsigned short)(sv.x & 0xFFFFu));
            float a1 = bf2f((unsigned short)(sv.x >> 16));
            float a2 = bf2f((unsigned short)(sv.y & 0xFFFFu));
            float a3 = bf2f((unsigned short)(sv.y >> 16));
            int maxd = deg;
            maxd = max(maxd, __shfl_xor(maxd, 16, 64));
            maxd = max(maxd, __shfl_xor(maxd, 32, 64));
            for (int j = 0; j < maxd; j += 8) {
                unsigned uu[8];
                #pragma unroll
                for (int k = 0; k < 8; ++k) {
                    int jc = j + k; jc = jc < cmax ? jc : cmax;   // clamp
                    uu[k] = bdata[c0 + jc];
                }
                uint2 hv[8];
                #pragma unroll
                for (int k = 0; k < 8; ++k) {
                    unsigned src = uu[k];
                    if (src > (unsigned)(N_NODES - 1)) src = N_NODES - 1;
                    hv[k] = *(const uint2*)(hs + (size_t)src * DOUT + fl * 4);
                }
                #pragma unroll
                for (int k = 0; k < 8; ++k) {
                    bool valid = (j + k) < deg;
                    unsigned x = valid ? hv[k].x : 0u;   // cndmask, no branch
                    unsigned y = valid ? hv[k].y : 0u;
                    a0 += bf2f((unsigned short)(x & 0xFFFFu));
                    a1 += bf2f((unsigned short)(x >> 16));
                    a2 += bf2f((unsigned short)(y & 0xFFFFu));
                    a3 += bf2f((unsigned short)(y >> 16));
                }
            }
            float di = dinv[node];
            float4 b4  = ((const float4*)bias)[fl];
            float4 g4  = ((const float4*)gamma)[fl];
            float4 be4 = ((const float4*)beta)[fl];
            a0 = a0 * di + b4.x;
            a1 = a1 * di + b4.y;
            a2 = a2 * di + b4.z;
            a3 = a3 * di + b4.w;
            float sum = (a0 + a1) + (a2 + a3);
            #pragma unroll
            for (int d = 1; d < 16; d <<= 1) sum += __shfl_xor(sum, d, 64);
            float mu = sum * (1.0f / 64.0f);
            float d0 = a0 - mu, d1 = a1 - mu, d2 = a2 - mu, d3 = a3 - mu;
            float vs = (d0 * d0 + d1 * d1) + (d2 * d2 + d3 * d3);
            #pragma unroll
            for (int d = 1; d < 16; d <<= 1) vs += __shfl_xor(vs, d, 64);
            float var = vs * (1.0f / 64.0f);
            float rinv = rsqrtf(var + LN_EPS);
            float4 ov;
            ov.x = d0 * rinv * g4.x + be4.x;
            ov.y = d1 * rinv * g4.y + be4.y;
            ov.z = d2 * rinv * g4.z + be4.z;
            ov.w = d3 * rinv * g4.w + be4.w;
            *(float4*)(out + (size_t)node * DOUT + fl * 4) = ov;
        }
    }
}

extern "C" void kernel_launch(void* const* d_in, const int* in_sizes, int n_in,
                              void* d_out, int out_size, void* d_ws, size_t ws_size,
                              hipStream_t stream) {
    const float* xs    = (const float*)d_in[0];
    const int*   ei    = (const int*)d_in[1];
    const float* W     = (const float*)d_in[2];
    const float* bias  = (const float*)d_in[3];
    const float* gamma = (const float*)d_in[4];
    const float* beta  = (const float*)d_in[5];
    float* out = (float*)d_out;

    char* base = (char*)d_ws;
    auto align_up = [](size_t x) { return (x + 255) & ~(size_t)255; };
    size_t o = 0;
    int* gcur   = (int*)(base + o);      o = align_up(o + (size_t)NB * 4);
    float* dinv = (float*)(base + o);    o = align_up(o + (size_t)N_NODES * 4);
    unsigned* bdata = (unsigned*)(base + o);           // becomes sorted csr
    o = align_up(o + (size_t)NB * BCAP * 4);
    unsigned short* hs = (unsigned short*)(base + o);
    o = align_up(o + (size_t)N_NODES * DOUT * 2);
    int* nstart = (int*)(base + o);      o = align_up(o + (size_t)N_NODES * 4);
    int* nend   = (int*)(base + o);      o = align_up(o + (size_t)N_NODES * 4);
    (void)ws_size; (void)in_sizes; (void)n_in; (void)out_size;

    void* args[] = {(void*)&xs, (void*)&ei, (void*)&W, (void*)&bias,
                    (void*)&gamma, (void*)&beta, (void*)&gcur, (void*)&dinv,
                    (void*)&bdata, (void*)&hs, (void*)&nstart, (void*)&nend,
                    (void*)&out};
    hipLaunchCooperativeKernel((const void*)fused_kernel, dim3(GRID), dim3(512),
                               args, 0, stream);
}

// Round 17
// 153.135 us; speedup vs baseline: 1.5962x; 1.5962x over previous
//
#include <hip/hip_runtime.h>
#include <hip/hip_cooperative_groups.h>

namespace cg = cooperative_groups;

#define N_NODES 50000
#define N_EDGES 800000
#define DIN 256
#define DOUT 64
#define LN_EPS 1e-5f
#define NB 782        // buckets of 64 dsts (= 2 * GRID exactly)
#define BCAP 2048     // bucket capacity (mean 1024, sd ~32)
#define GRID 391      // prep blocks; 391 * 2048 edges = 800768 >= 800000
#define EPB 2048      // partition edges/block

typedef __attribute__((ext_vector_type(8))) short bfrag8;
typedef __attribute__((ext_vector_type(4))) float f32x4;

__device__ inline unsigned short f2bf(float f) {
    unsigned u = __builtin_bit_cast(unsigned, f);
    u += 0x7fffu + ((u >> 16) & 1u);          // round-to-nearest-even
    return (unsigned short)(u >> 16);
}
__device__ inline float bf2f(unsigned short b) {
    unsigned u = ((unsigned)b) << 16;
    return __builtin_bit_cast(float, u);
}

// ---- cooperative prep: zero -> partition -> sort/dinv (all low-VGPR phases) --
// Fuses the 3 atomic-bound stages; grid.sync replaces 2 kernel boundaries.
// gemm/agg stay standalone so their register allocations are untouched (R16
// lesson: one shared allocation broke the MFMA + load-batching phases).
__global__ __launch_bounds__(512) void prep_kernel(
    const int* __restrict__ ei, int* __restrict__ gcur,
    unsigned* __restrict__ bdata, float* __restrict__ dinv,
    int* __restrict__ nstart, int* __restrict__ nend) {
    cg::grid_group grid = cg::this_grid();
    __shared__ __align__(16) char smraw[8704];
    const int tid = threadIdx.x;

    // ---------- phase 0: zero gcur ----------
    {
        int i = blockIdx.x * 512 + tid;
        if (i < NB) gcur[i] = 0;
    }
    grid.sync();

    // ---------- phase 1: partition (bucket edges by dst/64, rank trick) ------
    {
        int* hist  = (int*)smraw;
        int* hbase = hist + NB;
        for (int c = tid; c < NB; c += 512) hist[c] = 0;
        __syncthreads();
        const int chunk = blockIdx.x * EPB;
        unsigned u[4]; int bk[4]; int rk[4];
        #pragma unroll
        for (int i = 0; i < 4; ++i) {
            int e = chunk + i * 512 + tid;
            if (e < N_EDGES) {
                int s = ei[e];
                int d = ei[N_EDGES + e];
                u[i] = (unsigned)s | ((unsigned)(d & 63) << 17);
                bk[i] = d >> 6;
                rk[i] = atomicAdd(&hist[bk[i]], 1);
            } else { bk[i] = -1; u[i] = 0; rk[i] = 0; }
        }
        __syncthreads();
        for (int c = tid; c < NB; c += 512) {
            int n = hist[c];
            hbase[c] = n ? atomicAdd(&gcur[c], n) : 0;
        }
        __syncthreads();
        #pragma unroll
        for (int i = 0; i < 4; ++i) {
            if (bk[i] >= 0) {
                int off = hbase[bk[i]] + rk[i];
                if (off < BCAP) bdata[(size_t)bk[i] * BCAP + off] = u[i];
            }
        }
    }
    grid.sync();

    // ---------- phase 2: counting sort (2 buckets/block) + dinv + bounds -----
    {
        unsigned* buf = (unsigned*)smraw;            // 8KB
        int* hist = (int*)(smraw + BCAP * 4);
        int* pre  = hist + 64;
        #pragma unroll
        for (int t2 = 0; t2 < 2; ++t2) {
            int b = blockIdx.x * 2 + t2;             // 0..781, always valid
            if (tid < 64) hist[tid] = 0;
            __syncthreads();
            int cntb = gcur[b];
            if (cntb > BCAP) cntb = BCAP;
            unsigned* bd = bdata + (size_t)b * BCAP;
            unsigned v[4]; int rk[4];
            #pragma unroll
            for (int j = 0; j < 4; ++j) {
                int i = tid + j * 512;
                if (i < cntb) {
                    v[j] = bd[i];
                    rk[j] = atomicAdd(&hist[v[j] >> 17], 1);
                } else { v[j] = 0; rk[j] = -1; }
            }
            __syncthreads();
            if (tid < 64) {                          // wave 0: exclusive scan
                int n = hist[tid], s = n;
                #pragma unroll
                for (int d = 1; d < 64; d <<= 1) {
                    int t = __shfl_up(s, d, 64);
                    if (tid >= d) s += t;
                }
                pre[tid] = s - n;
                int node = b * 64 + tid;
                if (node < N_NODES) {
                    dinv[node] = rsqrtf((float)(n + 1));   // +1 self loop
                    nstart[node] = b * BCAP + (s - n);
                    nend[node]   = b * BCAP + s;
                }
            }
            __syncthreads();
            #pragma unroll
            for (int j = 0; j < 4; ++j) {
                if (rk[j] >= 0)
                    buf[pre[v[j] >> 17] + rk[j]] = v[j] & 0x1FFFF;   // src only
            }
            __syncthreads();
            #pragma unroll
            for (int j = 0; j < 4; ++j) {
                int i = tid + j * 512;
                if (i < cntb) bd[i] = buf[i];        // coalesced writeback
            }
            __syncthreads();
        }
    }
}

// ------- MFMA GEMM: hs[n][d] = (sum_k xs[n][k] * W[d][k]) * dinv[n], bf16 ----
__global__ __launch_bounds__(512) void gemm_kernel(const float* __restrict__ xs,
                                                   const float* __restrict__ W,
                                                   const float* __restrict__ dinv,
                                                   unsigned short* __restrict__ hs) {
    __shared__ bfrag8 wg[64 * 32];   // 32KB bf16 W
    const int tid = threadIdx.x;
    #pragma unroll
    for (int i = 0; i < 4; ++i) {
        int gi = tid + i * 512;              // 0..2047
        int d = gi >> 5, g = gi & 31;
        const float* src = W + d * 256 + g * 8;
        f32x4 f0 = *(const f32x4*)src;
        f32x4 f1 = *(const f32x4*)(src + 4);
        union { unsigned short us[8]; bfrag8 v; } p;
        p.us[0] = f2bf(f0.x); p.us[1] = f2bf(f0.y);
        p.us[2] = f2bf(f0.z); p.us[3] = f2bf(f0.w);
        p.us[4] = f2bf(f1.x); p.us[5] = f2bf(f1.y);
        p.us[6] = f2bf(f1.z); p.us[7] = f2bf(f1.w);
        wg[d * 32 + (g ^ (d & 7))] = p.v;
    }
    __syncthreads();

    const int lane = tid & 63, wv = tid >> 6;
    const int n0 = (blockIdx.x * 8 + wv) * 16;
    int arow = n0 + (lane & 15);
    if (arow >= N_NODES) arow = N_NODES - 1;          // clamp (loads only)
    const float* xrow = xs + (size_t)arow * DIN + (lane >> 4) * 8;

    f32x4 acc[4] = {{0.f, 0.f, 0.f, 0.f}, {0.f, 0.f, 0.f, 0.f},
                    {0.f, 0.f, 0.f, 0.f}, {0.f, 0.f, 0.f, 0.f}};
    const int swz = lane & 7;
    #pragma unroll
    for (int s = 0; s < 8; ++s) {
        f32x4 xa = *(const f32x4*)(xrow + s * 32);
        f32x4 xb = *(const f32x4*)(xrow + s * 32 + 4);
        union { unsigned short us[8]; bfrag8 v; } a;
        a.us[0] = f2bf(xa.x); a.us[1] = f2bf(xa.y);
        a.us[2] = f2bf(xa.z); a.us[3] = f2bf(xa.w);
        a.us[4] = f2bf(xb.x); a.us[5] = f2bf(xb.y);
        a.us[6] = f2bf(xb.z); a.us[7] = f2bf(xb.w);
        int g = s * 4 + (lane >> 4);
        #pragma unroll
        for (int t = 0; t < 4; ++t) {
            bfrag8 b = wg[(t * 16 + (lane & 15)) * 32 + (g ^ swz)];
            acc[t] = __builtin_amdgcn_mfma_f32_16x16x32_bf16(a.v, b, acc[t], 0, 0, 0);
        }
    }
    // C/D: col = lane&15, row = (lane>>4)*4 + r ; scale by dinv[row] on store
    #pragma unroll
    for (int t = 0; t < 4; ++t) {
        #pragma unroll
        for (int r = 0; r < 4; ++r) {
            int row = n0 + (lane >> 4) * 4 + r;
            if (row < N_NODES) {
                float dr = dinv[row];
                hs[(size_t)row * DOUT + t * 16 + (lane & 15)] = f2bf(acc[t][r] * dr);
            }
        }
    }
}

// -------- CSR aggregate: 4 nodes/wave, 16 lanes/node, uint2 (4 bf16)/lane ----
// (R12 measured-best shape: 8-deep unroll)
__global__ __launch_bounds__(256) void csr_agg_ln_kernel(
    const unsigned* __restrict__ csr, const int* __restrict__ nstart,
    const int* __restrict__ nend, const unsigned short* __restrict__ hs,
    const float* __restrict__ dinv, const float* __restrict__ bias,
    const float* __restrict__ gamma, const float* __restrict__ beta,
    float* __restrict__ out) {
    const int tid = threadIdx.x, lane = tid & 63, wv = tid >> 6;
    const int q = lane >> 4;          // which of the wave's 4 nodes
    const int fl = lane & 15;         // feature group (4 feats) within node
    const int node = (blockIdx.x * 4 + wv) * 4 + q;
    if (node >= N_NODES) return;
    const int c0 = nstart[node];
    const int deg = nend[node] - c0;
    const int cmax = deg > 0 ? deg - 1 : 0;

    // self loop (hs pre-scaled by dinv[src])
    uint2 sv = *(const uint2*)(hs + (size_t)node * DOUT + fl * 4);
    float a0 = bf2f((unsigned short)(sv.x & 0xFFFFu));
    float a1 = bf2f((unsigned short)(sv.x >> 16));
    float a2 = bf2f((unsigned short)(sv.y & 0xFFFFu));
    float a3 = bf2f((unsigned short)(sv.y >> 16));

    int maxd = deg;
    maxd = max(maxd, __shfl_xor(maxd, 16, 64));
    maxd = max(maxd, __shfl_xor(maxd, 32, 64));

    for (int j = 0; j < maxd; j += 8) {
        unsigned uu[8];
        #pragma unroll
        for (int k = 0; k < 8; ++k) {
            int jc = j + k; jc = jc < cmax ? jc : cmax;   // clamp, unconditional
            uu[k] = csr[c0 + jc];
        }
        uint2 hv[8];
        #pragma unroll
        for (int k = 0; k < 8; ++k) {
            unsigned src = uu[k];
            if (src > (unsigned)(N_NODES - 1)) src = N_NODES - 1;
            hv[k] = *(const uint2*)(hs + (size_t)src * DOUT + fl * 4);
        }
        #pragma unroll
        for (int k = 0; k < 8; ++k) {
            bool valid = (j + k) < deg;
            unsigned x = valid ? hv[k].x : 0u;   // cndmask, no branch
            unsigned y = valid ? hv[k].y : 0u;
            a0 += bf2f((unsigned short)(x & 0xFFFFu));
            a1 += bf2f((unsigned short)(x >> 16));
            a2 += bf2f((unsigned short)(y & 0xFFFFu));
            a3 += bf2f((unsigned short)(y >> 16));
        }
    }
    float di = dinv[node];
    float4 b4  = ((const float4*)bias)[fl];
    float4 g4  = ((const float4*)gamma)[fl];
    float4 be4 = ((const float4*)beta)[fl];
    a0 = a0 * di + b4.x;
    a1 = a1 * di + b4.y;
    a2 = a2 * di + b4.z;
    a3 = a3 * di + b4.w;
    // LayerNorm over 64 features = 16-lane group x 4 per lane
    float sum = (a0 + a1) + (a2 + a3);
    #pragma unroll
    for (int d = 1; d < 16; d <<= 1) sum += __shfl_xor(sum, d, 64);
    float mu = sum * (1.0f / 64.0f);
    float d0 = a0 - mu, d1 = a1 - mu, d2 = a2 - mu, d3 = a3 - mu;
    float vs = (d0 * d0 + d1 * d1) + (d2 * d2 + d3 * d3);
    #pragma unroll
    for (int d = 1; d < 16; d <<= 1) vs += __shfl_xor(vs, d, 64);
    float var = vs * (1.0f / 64.0f);
    float rinv = rsqrtf(var + LN_EPS);
    float4 ov;
    ov.x = d0 * rinv * g4.x + be4.x;
    ov.y = d1 * rinv * g4.y + be4.y;
    ov.z = d2 * rinv * g4.z + be4.z;
    ov.w = d3 * rinv * g4.w + be4.w;
    *(float4*)(out + (size_t)node * DOUT + fl * 4) = ov;
}

extern "C" void kernel_launch(void* const* d_in, const int* in_sizes, int n_in,
                              void* d_out, int out_size, void* d_ws, size_t ws_size,
                              hipStream_t stream) {
    const float* xs    = (const float*)d_in[0];
    const int*   ei    = (const int*)d_in[1];
    const float* W     = (const float*)d_in[2];
    const float* bias  = (const float*)d_in[3];
    const float* gamma = (const float*)d_in[4];
    const float* beta  = (const float*)d_in[5];
    float* out = (float*)d_out;

    char* base = (char*)d_ws;
    auto align_up = [](size_t x) { return (x + 255) & ~(size_t)255; };
    size_t o = 0;
    int* gcur   = (int*)(base + o);      o = align_up(o + (size_t)NB * 4);
    float* dinv = (float*)(base + o);    o = align_up(o + (size_t)N_NODES * 4);
    unsigned* bdata = (unsigned*)(base + o);           // becomes sorted csr
    o = align_up(o + (size_t)NB * BCAP * 4);
    unsigned short* hs = (unsigned short*)(base + o);
    o = align_up(o + (size_t)N_NODES * DOUT * 2);
    int* nstart = (int*)(base + o);      o = align_up(o + (size_t)N_NODES * 4);
    int* nend   = (int*)(base + o);      o = align_up(o + (size_t)N_NODES * 4);
    (void)ws_size; (void)in_sizes; (void)n_in; (void)out_size;

    void* args[] = {(void*)&ei, (void*)&gcur, (void*)&bdata, (void*)&dinv,
                    (void*)&nstart, (void*)&nend};
    hipLaunchCooperativeKernel((const void*)prep_kernel, dim3(GRID), dim3(512),
                               args, 0, stream);
    gemm_kernel<<<(N_NODES + 127) / 128, 512, 0, stream>>>(xs, W, dinv, hs);
    csr_agg_ln_kernel<<<(N_NODES + 15) / 16, 256, 0, stream>>>(
        bdata, nstart, nend, hs, dinv, bias, gamma, beta, out);
}

// Round 18
// 61.213 us; speedup vs baseline: 3.9930x; 2.5017x over previous
//
#include <hip/hip_runtime.h>

#define N_NODES 50000
#define N_EDGES 800000
#define DIN 256
#define DOUT 64
#define LN_EPS 1e-5f
#define NB 782        // buckets of 64 dsts
#define BCAP 2048     // bucket capacity (mean 1024, sd ~32)
#define PBLK 391      // partition blocks; 391 * 2048 = 800768 >= 800000
#define EPB 2048      // partition edges/block

typedef __attribute__((ext_vector_type(8))) short bfrag8;
typedef __attribute__((ext_vector_type(4))) float f32x4;

__device__ inline unsigned short f2bf(float f) {
    unsigned u = __builtin_bit_cast(unsigned, f);
    u += 0x7fffu + ((u >> 16) & 1u);          // round-to-nearest-even
    return (unsigned short)(u >> 16);
}
__device__ inline float bf2f(unsigned short b) {
    unsigned u = ((unsigned)b) << 16;
    return __builtin_bit_cast(float, u);
}

// ---------------- zero gcur ----------------
__global__ void zero_gcur_kernel(int* __restrict__ gcur) {
    int i = blockIdx.x * 256 + threadIdx.x;
    if (i < NB) gcur[i] = 0;
}

// ------- heterogeneous kernel: blocks 0..390 partition, 391..781 gemm --------
// The two roles are independent (h is UNSCALED now, so gemm needs no dinv):
// latency-bound partition hides under memory-bound gemm, one dispatch saved.
// Block-uniform role branch; each role keeps its standalone code shape.
__global__ __launch_bounds__(512) void part_gemm_kernel(
    const int* __restrict__ ei, int* __restrict__ gcur, unsigned* __restrict__ bdata,
    const float* __restrict__ xs, const float* __restrict__ W,
    unsigned short* __restrict__ h) {
    __shared__ __align__(16) char smraw[32768];
    const int tid = threadIdx.x;
    if (blockIdx.x < PBLK) {
        // ================= partition role =================
        int* hist  = (int*)smraw;
        int* hbase = hist + NB;
        for (int c = tid; c < NB; c += 512) hist[c] = 0;
        __syncthreads();
        const int chunk = blockIdx.x * EPB;
        unsigned u[4]; int bk[4]; int rk[4];
        #pragma unroll
        for (int i = 0; i < 4; ++i) {
            int e = chunk + i * 512 + tid;
            if (e < N_EDGES) {
                int s = ei[e];
                int d = ei[N_EDGES + e];
                u[i] = (unsigned)s | ((unsigned)(d & 63) << 17);
                bk[i] = d >> 6;
                rk[i] = atomicAdd(&hist[bk[i]], 1);
            } else { bk[i] = -1; u[i] = 0; rk[i] = 0; }
        }
        __syncthreads();
        for (int c = tid; c < NB; c += 512) {
            int n = hist[c];
            hbase[c] = n ? atomicAdd(&gcur[c], n) : 0;
        }
        __syncthreads();
        #pragma unroll
        for (int i = 0; i < 4; ++i) {
            if (bk[i] >= 0) {
                int off = hbase[bk[i]] + rk[i];
                if (off < BCAP) bdata[(size_t)bk[i] * BCAP + off] = u[i];
            }
        }
    } else {
        // ================= gemm role: h[n][d] = sum_k xs[n][k]*W[d][k], bf16 =
        bfrag8* wg = (bfrag8*)smraw;                 // 32KB bf16 W
        #pragma unroll
        for (int i = 0; i < 4; ++i) {
            int gi = tid + i * 512;                  // 0..2047
            int d = gi >> 5, g = gi & 31;
            const float* src = W + d * 256 + g * 8;
            f32x4 f0 = *(const f32x4*)src;
            f32x4 f1 = *(const f32x4*)(src + 4);
            union { unsigned short us[8]; bfrag8 v; } p;
            p.us[0] = f2bf(f0.x); p.us[1] = f2bf(f0.y);
            p.us[2] = f2bf(f0.z); p.us[3] = f2bf(f0.w);
            p.us[4] = f2bf(f1.x); p.us[5] = f2bf(f1.y);
            p.us[6] = f2bf(f1.z); p.us[7] = f2bf(f1.w);
            wg[d * 32 + (g ^ (d & 7))] = p.v;
        }
        __syncthreads();
        const int lane = tid & 63, wv = tid >> 6;
        const int bid = blockIdx.x - PBLK;           // 0..390
        const int n0 = (bid * 8 + wv) * 16;          // 391*128 = 50048 >= 50000
        int arow = n0 + (lane & 15);
        if (arow >= N_NODES) arow = N_NODES - 1;     // clamp (loads only)
        const float* xrow = xs + (size_t)arow * DIN + (lane >> 4) * 8;
        f32x4 acc[4] = {{0.f, 0.f, 0.f, 0.f}, {0.f, 0.f, 0.f, 0.f},
                        {0.f, 0.f, 0.f, 0.f}, {0.f, 0.f, 0.f, 0.f}};
        const int swz = lane & 7;
        #pragma unroll
        for (int s = 0; s < 8; ++s) {
            f32x4 xa = *(const f32x4*)(xrow + s * 32);
            f32x4 xb = *(const f32x4*)(xrow + s * 32 + 4);
            union { unsigned short us[8]; bfrag8 v; } a;
            a.us[0] = f2bf(xa.x); a.us[1] = f2bf(xa.y);
            a.us[2] = f2bf(xa.z); a.us[3] = f2bf(xa.w);
            a.us[4] = f2bf(xb.x); a.us[5] = f2bf(xb.y);
            a.us[6] = f2bf(xb.z); a.us[7] = f2bf(xb.w);
            int g = s * 4 + (lane >> 4);
            #pragma unroll
            for (int t = 0; t < 4; ++t) {
                bfrag8 b = wg[(t * 16 + (lane & 15)) * 32 + (g ^ swz)];
                acc[t] = __builtin_amdgcn_mfma_f32_16x16x32_bf16(a.v, b, acc[t], 0, 0, 0);
            }
        }
        // C/D: col = lane&15, row = (lane>>4)*4 + r
        #pragma unroll
        for (int t = 0; t < 4; ++t) {
            #pragma unroll
            for (int r = 0; r < 4; ++r) {
                int row = n0 + (lane >> 4) * 4 + r;
                if (row < N_NODES)
                    h[(size_t)row * DOUT + t * 16 + (lane & 15)] = f2bf(acc[t][r]);
            }
        }
    }
}

// ------ per-bucket counting sort by dst + dinv + per-node CSR bounds ---------
__global__ __launch_bounds__(512) void sort_dinv_kernel(
    unsigned* __restrict__ bdata, const int* __restrict__ gcur,
    float* __restrict__ dinv, int* __restrict__ nstart, int* __restrict__ nend) {
    __shared__ unsigned buf[BCAP];   // 8KB
    __shared__ int hist[64];
    __shared__ int pre[64];
    const int tid = threadIdx.x, b = blockIdx.x;
    if (tid < 64) hist[tid] = 0;
    __syncthreads();
    int cntb = gcur[b];
    if (cntb > BCAP) cntb = BCAP;
    unsigned* bd = bdata + (size_t)b * BCAP;
    unsigned v[4];
    int rk[4];
    #pragma unroll
    for (int j = 0; j < 4; ++j) {
        int i = tid + j * 512;
        if (i < cntb) {
            v[j] = bd[i];
            rk[j] = atomicAdd(&hist[v[j] >> 17], 1);
        } else { v[j] = 0; rk[j] = -1; }
    }
    __syncthreads();
    if (tid < 64) {                      // wave 0: exclusive scan of hist
        int n = hist[tid], s = n;
        #pragma unroll
        for (int d = 1; d < 64; d <<= 1) {
            int t = __shfl_up(s, d, 64);
            if (tid >= d) s += t;
        }
        pre[tid] = s - n;
        int node = b * 64 + tid;
        if (node < N_NODES) {
            dinv[node] = rsqrtf((float)(n + 1));   // +1 self loop
            nstart[node] = b * BCAP + (s - n);
            nend[node]   = b * BCAP + s;
        }
    }
    __syncthreads();
    #pragma unroll
    for (int j = 0; j < 4; ++j) {
        if (rk[j] >= 0)
            buf[pre[v[j] >> 17] + rk[j]] = v[j] & 0x1FFFF;   // src only
    }
    __syncthreads();
    #pragma unroll
    for (int j = 0; j < 4; ++j) {
        int i = tid + j * 512;
        if (i < cntb) bd[i] = buf[i];    // coalesced writeback
    }
}

// -------- CSR aggregate: 4 nodes/wave, 16 lanes/node, uint2 (4 bf16)/lane ----
// h is unscaled now: per-edge w = dinv[src] (broadcast L1 load), fmaf into acc.
__global__ __launch_bounds__(256) void csr_agg_ln_kernel(
    const unsigned* __restrict__ csr, const int* __restrict__ nstart,
    const int* __restrict__ nend, const unsigned short* __restrict__ h,
    const float* __restrict__ dinv, const float* __restrict__ bias,
    const float* __restrict__ gamma, const float* __restrict__ beta,
    float* __restrict__ out) {
    const int tid = threadIdx.x, lane = tid & 63, wv = tid >> 6;
    const int q = lane >> 4;          // which of the wave's 4 nodes
    const int fl = lane & 15;         // feature group (4 feats) within node
    const int node = (blockIdx.x * 4 + wv) * 4 + q;
    if (node >= N_NODES) return;
    const int c0 = nstart[node];
    const int deg = nend[node] - c0;
    const int cmax = deg > 0 ? deg - 1 : 0;
    const float di = dinv[node];

    // self loop: h[node] * dinv[node]
    uint2 sv = *(const uint2*)(h + (size_t)node * DOUT + fl * 4);
    float a0 = bf2f((unsigned short)(sv.x & 0xFFFFu)) * di;
    float a1 = bf2f((unsigned short)(sv.x >> 16)) * di;
    float a2 = bf2f((unsigned short)(sv.y & 0xFFFFu)) * di;
    float a3 = bf2f((unsigned short)(sv.y >> 16)) * di;

    int maxd = deg;
    maxd = max(maxd, __shfl_xor(maxd, 16, 64));
    maxd = max(maxd, __shfl_xor(maxd, 32, 64));

    for (int j = 0; j < maxd; j += 8) {
        unsigned uu[8];
        #pragma unroll
        for (int k = 0; k < 8; ++k) {
            int jc = j + k; jc = jc < cmax ? jc : cmax;   // clamp, unconditional
            uu[k] = csr[c0 + jc];
        }
        uint2 hv[8];
        float w[8];
        #pragma unroll
        for (int k = 0; k < 8; ++k) {
            unsigned src = uu[k];
            if (src > (unsigned)(N_NODES - 1)) src = N_NODES - 1;
            hv[k] = *(const uint2*)(h + (size_t)src * DOUT + fl * 4);
            w[k] = dinv[src];
        }
        #pragma unroll
        for (int k = 0; k < 8; ++k) {
            bool valid = (j + k) < deg;
            unsigned x = valid ? hv[k].x : 0u;   // cndmask, no branch
            unsigned y = valid ? hv[k].y : 0u;
            a0 = fmaf(bf2f((unsigned short)(x & 0xFFFFu)), w[k], a0);
            a1 = fmaf(bf2f((unsigned short)(x >> 16)), w[k], a1);
            a2 = fmaf(bf2f((unsigned short)(y & 0xFFFFu)), w[k], a2);
            a3 = fmaf(bf2f((unsigned short)(y >> 16)), w[k], a3);
        }
    }
    float4 b4  = ((const float4*)bias)[fl];
    float4 g4  = ((const float4*)gamma)[fl];
    float4 be4 = ((const float4*)beta)[fl];
    a0 = a0 * di + b4.x;
    a1 = a1 * di + b4.y;
    a2 = a2 * di + b4.z;
    a3 = a3 * di + b4.w;
    // LayerNorm over 64 features = 16-lane group x 4 per lane
    float sum = (a0 + a1) + (a2 + a3);
    #pragma unroll
    for (int d = 1; d < 16; d <<= 1) sum += __shfl_xor(sum, d, 64);
    float mu = sum * (1.0f / 64.0f);
    float d0 = a0 - mu, d1 = a1 - mu, d2 = a2 - mu, d3 = a3 - mu;
    float vs = (d0 * d0 + d1 * d1) + (d2 * d2 + d3 * d3);
    #pragma unroll
    for (int d = 1; d < 16; d <<= 1) vs += __shfl_xor(vs, d, 64);
    float var = vs * (1.0f / 64.0f);
    float rinv = rsqrtf(var + LN_EPS);
    float4 ov;
    ov.x = d0 * rinv * g4.x + be4.x;
    ov.y = d1 * rinv * g4.y + be4.y;
    ov.z = d2 * rinv * g4.z + be4.z;
    ov.w = d3 * rinv * g4.w + be4.w;
    *(float4*)(out + (size_t)node * DOUT + fl * 4) = ov;
}

extern "C" void kernel_launch(void* const* d_in, const int* in_sizes, int n_in,
                              void* d_out, int out_size, void* d_ws, size_t ws_size,
                              hipStream_t stream) {
    const float* xs    = (const float*)d_in[0];
    const int*   ei    = (const int*)d_in[1];
    const float* W     = (const float*)d_in[2];
    const float* bias  = (const float*)d_in[3];
    const float* gamma = (const float*)d_in[4];
    const float* beta  = (const float*)d_in[5];
    float* out = (float*)d_out;

    char* base = (char*)d_ws;
    auto align_up = [](size_t x) { return (x + 255) & ~(size_t)255; };
    size_t o = 0;
    int* gcur   = (int*)(base + o);      o = align_up(o + (size_t)NB * 4);
    float* dinv = (float*)(base + o);    o = align_up(o + (size_t)N_NODES * 4);
    unsigned* bdata = (unsigned*)(base + o);           // becomes sorted csr
    o = align_up(o + (size_t)NB * BCAP * 4);
    unsigned short* h = (unsigned short*)(base + o);
    o = align_up(o + (size_t)N_NODES * DOUT * 2);
    int* nstart = (int*)(base + o);      o = align_up(o + (size_t)N_NODES * 4);
    int* nend   = (int*)(base + o);      o = align_up(o + (size_t)N_NODES * 4);
    (void)ws_size; (void)in_sizes; (void)n_in; (void)out_size;

    zero_gcur_kernel<<<(NB + 255) / 256, 256, 0, stream>>>(gcur);
    part_gemm_kernel<<<2 * PBLK, 512, 0, stream>>>(ei, gcur, bdata, xs, W, h);
    sort_dinv_kernel<<<NB, 512, 0, stream>>>(bdata, gcur, dinv, nstart, nend);
    csr_agg_ln_kernel<<<(N_NODES + 15) / 16, 256, 0, stream>>>(
        bdata, nstart, nend, h, dinv, bias, gamma, beta, out);
}